// Round 12
// baseline (266.987 us; speedup 1.0000x reference)
//
#include <hip/hip_runtime.h>

#define F0 128
#define F1 64
#define F2 32

__device__ __forceinline__ int rfl(int v) { return __builtin_amdgcn_readfirstlane(v); }

// bf16 helpers (RNE)
__device__ __forceinline__ unsigned short f2b(float f) {
    unsigned u = __float_as_uint(f);
    return (unsigned short)((u + 0x7fffu + ((u >> 16) & 1u)) >> 16);
}
__device__ __forceinline__ float b2f(unsigned short u) {
    return __uint_as_float(((unsigned)u) << 16);
}

// ---------------- degree ----------------
__global__ void deg_count(const int* __restrict__ dst, int* __restrict__ deg, int E) {
    int e = blockIdx.x * blockDim.x + threadIdx.x;
    if (e < E) atomicAdd(&deg[dst[e]], 1);
}

// ---------------- scan (3 kernels; round-9 post-mortem: single-block fused scan
// was 135 us latency-bound on one CU — multi-block version is ~5 us) ----------------
__global__ void scan1(const int* __restrict__ deg, float* __restrict__ dinv,
                      int* __restrict__ rowptr, int* __restrict__ bsum, int N) {
    __shared__ int s[256];
    int i = blockIdx.x * 256 + threadIdx.x;
    int v = (i < N) ? deg[i] : 0;
    if (i < N) dinv[i] = rsqrtf((float)(v + 1));  // +1 self-loop
    s[threadIdx.x] = v;
    __syncthreads();
    for (int off = 1; off < 256; off <<= 1) {
        int t = 0;
        if (threadIdx.x >= off) t = s[threadIdx.x - off];
        __syncthreads();
        if (threadIdx.x >= off) s[threadIdx.x] += t;
        __syncthreads();
    }
    if (i < N) rowptr[i] = s[threadIdx.x] - v;
    if (threadIdx.x == 255) bsum[blockIdx.x] = s[255];
}

__global__ void scan2(int* __restrict__ bsum, int* __restrict__ boff, int nb) {
    __shared__ int s[256];
    int v = (threadIdx.x < nb) ? bsum[threadIdx.x] : 0;
    s[threadIdx.x] = v;
    __syncthreads();
    for (int off = 1; off < 256; off <<= 1) {
        int t = 0;
        if (threadIdx.x >= off) t = s[threadIdx.x - off];
        __syncthreads();
        if (threadIdx.x >= off) s[threadIdx.x] += t;
        __syncthreads();
    }
    if (threadIdx.x < nb) boff[threadIdx.x] = s[threadIdx.x] - v;
}

__global__ void scan3(int* __restrict__ rowptr, const int* __restrict__ boff,
                      int* __restrict__ cursor, int N) {
    int i = blockIdx.x * 256 + threadIdx.x;
    if (i < N) {
        int v = rowptr[i] + boff[blockIdx.x];
        rowptr[i] = v;
        cursor[i] = v;
    }
}

// ---------------- bucket, XCD-pinned by dst partition (blockIdx&7) ----------------
__global__ __launch_bounds__(256) void bucket8(const int* __restrict__ src,
                                               const int* __restrict__ dst,
                                               int* __restrict__ cursor,
                                               int* __restrict__ csr, int E, int N) {
    int part = blockIdx.x & 7;
    int g = blockIdx.x >> 3;
    int G = gridDim.x >> 3;
    int plo = (int)(((long long)N * part) >> 3);
    int phi = (int)(((long long)N * (part + 1)) >> 3);
    for (int e = g * 256 + threadIdx.x; e < E; e += G * 256) {
        int d = dst[e];
        if (d >= plo && d < phi) {
            int pos = atomicAdd(&cursor[d], 1);
            csr[pos] = src[e];
        }
    }
}

// ---------------- GEMM1: xws1b = bf16((x @ W1) * dinv[row])   [N,128]x[128,64] -------
// k-loop bound `kb` is a RUNTIME arg so the compiler cannot fully unroll
// (round-5 post-mortem: full unroll -> 256 VGPR -> 750 MB scratch spill).
__global__ __launch_bounds__(256) void gemm1(const float* __restrict__ x,
                                             const float* __restrict__ W1,
                                             const float* __restrict__ dinv,
                                             unsigned short* __restrict__ xws1b,
                                             int N, int kb) {
    __shared__ float sx[64][132];
    __shared__ float sW[64][64];
    int tid = threadIdx.x;
    int row0 = blockIdx.x * 64;

    for (int i = tid; i < 2048; i += 256) {
        int r = i >> 5, kq = i & 31;
        int gr = row0 + r;
        float4 v = make_float4(0.f, 0.f, 0.f, 0.f);
        if (gr < N) v = ((const float4*)(x + (size_t)gr * F0))[kq];
        *(float4*)(&sx[r][kq << 2]) = v;
    }

    int tx = tid & 15, ty = tid >> 4;
    int c0 = tx * 4, r0 = ty * 4;
    float acc[4][4] = {};

    const float4* W4 = (const float4*)W1;
    float4* sW4 = (float4*)(&sW[0][0]);

    for (int p = 0; p < 2; ++p) {
        if (p) __syncthreads();
        for (int i = tid; i < 1024; i += 256) sW4[i] = W4[p * 1024 + i];
        __syncthreads();
        int kbase = p * 64;
        for (int k = 0; k < kb; k += 4) {
            float a[4][4], b[4][4];
            #pragma unroll
            for (int rr = 0; rr < 4; ++rr)
                *(float4*)&a[rr][0] = *(const float4*)&sx[r0 + rr][kbase + k];
            #pragma unroll
            for (int j = 0; j < 4; ++j)
                *(float4*)&b[j][0] = *(const float4*)&sW[k + j][c0];
            #pragma unroll
            for (int j = 0; j < 4; ++j)
                #pragma unroll
                for (int rr = 0; rr < 4; ++rr)
                    #pragma unroll
                    for (int cc = 0; cc < 4; ++cc)
                        acc[rr][cc] += a[rr][j] * b[j][cc];
        }
    }

    #pragma unroll
    for (int rr = 0; rr < 4; ++rr) {
        int gr = row0 + r0 + rr;
        if (gr < N) {
            float s = dinv[gr];
            ushort4 o;
            o.x = f2b(acc[rr][0] * s); o.y = f2b(acc[rr][1] * s);
            o.z = f2b(acc[rr][2] * s); o.w = f2b(acc[rr][3] * s);
            *(ushort4*)&xws1b[gr * F1 + c0] = o;
        }
    }
}

// ---- gather1 + gemm2 fused, MLP-16: 16 independent gathers in flight ----
__global__ __launch_bounds__(256) void gather1f(const int* __restrict__ csr,
                                                const int* __restrict__ rowptr,
                                                const int* __restrict__ deg,
                                                const float* __restrict__ dinv,
                                                const unsigned short* __restrict__ xb,
                                                const float* __restrict__ b1,
                                                const float* __restrict__ W2,
                                                unsigned short* __restrict__ xws2b,
                                                int N, int kh) {
    __shared__ float sW2[F1][F2];    // 8 KB
    __shared__ float h1s[4][F1];     // 1 KB
    int tid = threadIdx.x;
    for (int i = tid; i < (F1 * F2) / 4; i += 256)
        ((float4*)&sW2[0][0])[i] = ((const float4*)W2)[i];
    __syncthreads();

    int wv = tid >> 6, lane = tid & 63;
    int node = blockIdx.x * 4 + wv;
    if (node >= N) return;
    int start = rfl(rowptr[node]);
    int cnt = rfl(deg[node]);

    float a[16];
    #pragma unroll
    for (int t = 0; t < 16; ++t) a[t] = 0.f;
    int j = 0;
    for (; j + 16 <= cnt; j += 16) {
        int s[16];
        #pragma unroll
        for (int t = 0; t < 16; ++t) s[t] = rfl(csr[start + j + t]);
        #pragma unroll
        for (int t = 0; t < 16; ++t) a[t] += b2f(xb[s[t] * F1 + lane]);
    }
    for (; j + 4 <= cnt; j += 4) {
        int s0 = rfl(csr[start + j]);
        int s1 = rfl(csr[start + j + 1]);
        int s2 = rfl(csr[start + j + 2]);
        int s3 = rfl(csr[start + j + 3]);
        a[0] += b2f(xb[s0 * F1 + lane]);
        a[1] += b2f(xb[s1 * F1 + lane]);
        a[2] += b2f(xb[s2 * F1 + lane]);
        a[3] += b2f(xb[s3 * F1 + lane]);
    }
    for (; j < cnt; ++j) {
        int s = rfl(csr[start + j]);
        a[0] += b2f(xb[s * F1 + lane]);
    }
    float acc = 0.f;
    #pragma unroll
    for (int t = 0; t < 16; ++t) acc += a[t];
    float dd = dinv[node];
    float h1v = fmaxf(dd * (acc + b2f(xb[node * F1 + lane])) + b1[lane], 0.f);

    h1s[wv][lane] = h1v;   // wave-local LDS round-trip

    int c = lane & 31, half = lane >> 5;
    int k0 = half * 32;
    float d0 = 0.f, d1 = 0.f, d2 = 0.f, d3 = 0.f;
    for (int k = 0; k < kh; k += 4) {
        d0 += h1s[wv][k0 + k]     * sW2[k0 + k][c];
        d1 += h1s[wv][k0 + k + 1] * sW2[k0 + k + 1][c];
        d2 += h1s[wv][k0 + k + 2] * sW2[k0 + k + 2][c];
        d3 += h1s[wv][k0 + k + 3] * sW2[k0 + k + 3][c];
    }
    float dot = (d0 + d1) + (d2 + d3);
    dot += __shfl_down(dot, 32, 64);
    if (half == 0) xws2b[node * F2 + c] = f2b(dot * dd);
}

// ---- gather2 + gemm3 fused, MLP-16 (8 per wave-half) ----
__global__ __launch_bounds__(256) void gather2f(const int* __restrict__ csr,
                                                const int* __restrict__ rowptr,
                                                const int* __restrict__ deg,
                                                const float* __restrict__ dinv,
                                                const unsigned short* __restrict__ xb,
                                                const float* __restrict__ b2,
                                                const float* __restrict__ Wl,
                                                const float* __restrict__ bl,
                                                float* __restrict__ out, int N, int kh) {
    __shared__ float sWl[F2][F0];    // 16 KB
    __shared__ float h2s[4][F2];     // 512 B
    int tid = threadIdx.x;
    for (int i = tid; i < (F2 * F0) / 4; i += 256)
        ((float4*)&sWl[0][0])[i] = ((const float4*)Wl)[i];
    __syncthreads();

    int wv = tid >> 6, lane = tid & 63;
    int node = blockIdx.x * 4 + wv;
    if (node >= N) return;
    int start = rfl(rowptr[node]);
    int cnt = rfl(deg[node]);
    int c = lane & 31, half = lane >> 5;

    float a[8];
    #pragma unroll
    for (int t = 0; t < 8; ++t) a[t] = 0.f;
    int j = 0;
    for (; j + 16 <= cnt; j += 16) {
        int s[16];
        #pragma unroll
        for (int t = 0; t < 16; ++t) s[t] = rfl(csr[start + j + t]);
        #pragma unroll
        for (int t = 0; t < 8; ++t) {
            int si = half ? s[2 * t + 1] : s[2 * t];
            a[t] += b2f(xb[si * F2 + c]);
        }
    }
    for (; j + 2 <= cnt; j += 2) {
        int s0 = rfl(csr[start + j]);
        int s1 = rfl(csr[start + j + 1]);
        int sa = half ? s1 : s0;
        a[0] += b2f(xb[sa * F2 + c]);
    }
    if (j < cnt) {
        int s = rfl(csr[start + j]);
        if (half == 0) a[0] += b2f(xb[s * F2 + c]);
    }
    float acc = 0.f;
    #pragma unroll
    for (int t = 0; t < 8; ++t) acc += a[t];
    acc += __shfl_down(acc, 32, 64);
    float dd = dinv[node];
    if (half == 0)
        h2s[wv][c] = fmaxf(dd * (acc + b2f(xb[node * F2 + c])) + b2[c], 0.f);

    float e0 = 0.f, e1 = 0.f, f0 = 0.f, f1 = 0.f;
    for (int k = 0; k < kh; k += 2) {
        float hk0 = h2s[wv][k], hk1 = h2s[wv][k + 1];
        e0 += hk0 * sWl[k][lane];
        e1 += hk1 * sWl[k + 1][lane];
        f0 += hk0 * sWl[k][lane + 64];
        f1 += hk1 * sWl[k + 1][lane + 64];
    }
    size_t ob = (size_t)node * F0;
    out[ob + lane]      = (e0 + e1) + bl[lane];
    out[ob + lane + 64] = (f0 + f1) + bl[lane + 64];
}

extern "C" void kernel_launch(void* const* d_in, const int* in_sizes, int n_in,
                              void* d_out, int out_size, void* d_ws, size_t ws_size,
                              hipStream_t stream) {
    const float* x  = (const float*)d_in[0];
    const int*   ei = (const int*)d_in[1];
    const float* W1 = (const float*)d_in[2];
    const float* b1 = (const float*)d_in[3];
    const float* W2 = (const float*)d_in[4];
    const float* b2 = (const float*)d_in[5];
    const float* Wl = (const float*)d_in[6];
    const float* bl = (const float*)d_in[7];
    float* out = (float*)d_out;

    const int N = in_sizes[0] / F0;   // 50000
    const int E = in_sizes[1] / 2;    // 800000
    const int* src = ei;
    const int* dst = ei + E;
    const int NB = (N + 255) / 256;   // 196

    char* ws = (char*)d_ws;
    size_t off = 0;
    auto alloc = [&](size_t bytes) {
        void* p = ws + off;
        off += (bytes + 255) & ~(size_t)255;
        return p;
    };
    int*            deg    = (int*)alloc((size_t)N * 4);
    float*          dinv   = (float*)alloc((size_t)N * 4);
    int*            rowptr = (int*)alloc((size_t)N * 4);
    int*            cursor = (int*)alloc((size_t)N * 4);
    int*            bsum   = (int*)alloc((size_t)NB * 4);
    int*            boff   = (int*)alloc((size_t)NB * 4);
    int*            csr    = (int*)alloc((size_t)E * 4);
    unsigned short* xws1b  = (unsigned short*)alloc((size_t)N * F1 * 2);
    unsigned short* xws2b  = (unsigned short*)alloc((size_t)N * F2 * 2);

    hipMemsetAsync(deg, 0, (size_t)N * 4, stream);
    deg_count<<<(E + 255) / 256, 256, 0, stream>>>(dst, deg, E);
    scan1<<<NB, 256, 0, stream>>>(deg, dinv, rowptr, bsum, N);
    scan2<<<1, 256, 0, stream>>>(bsum, boff, NB);
    scan3<<<NB, 256, 0, stream>>>(rowptr, boff, cursor, N);
    bucket8<<<1024, 256, 0, stream>>>(src, dst, cursor, csr, E, N);

    gemm1<<<(N + 63) / 64, 256, 0, stream>>>(x, W1, dinv, xws1b, N, 64);
    gather1f<<<(N + 3) / 4, 256, 0, stream>>>(csr, rowptr, deg, dinv, xws1b, b1, W2, xws2b, N, 32);
    gather2f<<<(N + 3) / 4, 256, 0, stream>>>(csr, rowptr, deg, dinv, xws2b, b2, Wl, bl, out, N, 32);
}

// Round 13
// 250.024 us; speedup vs baseline: 1.0678x; 1.0678x over previous
//
#include <hip/hip_runtime.h>

#define F0 128
#define F1 64
#define F2 32

__device__ __forceinline__ int rfl(int v) { return __builtin_amdgcn_readfirstlane(v); }

// bf16 helpers (RNE)
__device__ __forceinline__ unsigned short f2b(float f) {
    unsigned u = __float_as_uint(f);
    return (unsigned short)((u + 0x7fffu + ((u >> 16) & 1u)) >> 16);
}
__device__ __forceinline__ float b2f(unsigned short u) {
    return __uint_as_float(((unsigned)u) << 16);
}

// ---------------- degree ----------------
__global__ void deg_count(const int* __restrict__ dst, int* __restrict__ deg, int E) {
    int e = blockIdx.x * blockDim.x + threadIdx.x;
    if (e < E) atomicAdd(&deg[dst[e]], 1);
}

// ---------------- scan (3 kernels; round-9 post-mortem: single-block fused scan
// was 135 us latency-bound on one CU — multi-block version is ~5 us) ----------------
__global__ void scan1(const int* __restrict__ deg, float* __restrict__ dinv,
                      int* __restrict__ rowptr, int* __restrict__ bsum, int N) {
    __shared__ int s[256];
    int i = blockIdx.x * 256 + threadIdx.x;
    int v = (i < N) ? deg[i] : 0;
    if (i < N) dinv[i] = rsqrtf((float)(v + 1));  // +1 self-loop
    s[threadIdx.x] = v;
    __syncthreads();
    for (int off = 1; off < 256; off <<= 1) {
        int t = 0;
        if (threadIdx.x >= off) t = s[threadIdx.x - off];
        __syncthreads();
        if (threadIdx.x >= off) s[threadIdx.x] += t;
        __syncthreads();
    }
    if (i < N) rowptr[i] = s[threadIdx.x] - v;
    if (threadIdx.x == 255) bsum[blockIdx.x] = s[255];
}

__global__ void scan2(int* __restrict__ bsum, int* __restrict__ boff, int nb) {
    __shared__ int s[256];
    int v = (threadIdx.x < nb) ? bsum[threadIdx.x] : 0;
    s[threadIdx.x] = v;
    __syncthreads();
    for (int off = 1; off < 256; off <<= 1) {
        int t = 0;
        if (threadIdx.x >= off) t = s[threadIdx.x - off];
        __syncthreads();
        if (threadIdx.x >= off) s[threadIdx.x] += t;
        __syncthreads();
    }
    if (threadIdx.x < nb) boff[threadIdx.x] = s[threadIdx.x] - v;
}

__global__ void scan3(int* __restrict__ rowptr, const int* __restrict__ boff,
                      int* __restrict__ cursor, int N) {
    int i = blockIdx.x * 256 + threadIdx.x;
    if (i < N) {
        int v = rowptr[i] + boff[blockIdx.x];
        rowptr[i] = v;
        cursor[i] = v;
    }
}

// ---------------- bucket, XCD-pinned by dst partition (blockIdx&7) ----------------
__global__ __launch_bounds__(256) void bucket8(const int* __restrict__ src,
                                               const int* __restrict__ dst,
                                               int* __restrict__ cursor,
                                               int* __restrict__ csr, int E, int N) {
    int part = blockIdx.x & 7;
    int g = blockIdx.x >> 3;
    int G = gridDim.x >> 3;
    int plo = (int)(((long long)N * part) >> 3);
    int phi = (int)(((long long)N * (part + 1)) >> 3);
    for (int e = g * 256 + threadIdx.x; e < E; e += G * 256) {
        int d = dst[e];
        if (d >= plo && d < phi) {
            int pos = atomicAdd(&cursor[d], 1);
            csr[pos] = src[e];
        }
    }
}

// ---------------- GEMM1: xws1b = bf16((x @ W1) * dinv[row])   [N,128]x[128,64] -------
// k-loop bound `kb` is a RUNTIME arg so the compiler cannot fully unroll
// (round-5 post-mortem: full unroll -> 256 VGPR -> 750 MB scratch spill).
__global__ __launch_bounds__(256) void gemm1(const float* __restrict__ x,
                                             const float* __restrict__ W1,
                                             const float* __restrict__ dinv,
                                             unsigned short* __restrict__ xws1b,
                                             int N, int kb) {
    __shared__ float sx[64][132];
    __shared__ float sW[64][64];
    int tid = threadIdx.x;
    int row0 = blockIdx.x * 64;

    for (int i = tid; i < 2048; i += 256) {
        int r = i >> 5, kq = i & 31;
        int gr = row0 + r;
        float4 v = make_float4(0.f, 0.f, 0.f, 0.f);
        if (gr < N) v = ((const float4*)(x + (size_t)gr * F0))[kq];
        *(float4*)(&sx[r][kq << 2]) = v;
    }

    int tx = tid & 15, ty = tid >> 4;
    int c0 = tx * 4, r0 = ty * 4;
    float acc[4][4] = {};

    const float4* W4 = (const float4*)W1;
    float4* sW4 = (float4*)(&sW[0][0]);

    for (int p = 0; p < 2; ++p) {
        if (p) __syncthreads();
        for (int i = tid; i < 1024; i += 256) sW4[i] = W4[p * 1024 + i];
        __syncthreads();
        int kbase = p * 64;
        for (int k = 0; k < kb; k += 4) {
            float a[4][4], b[4][4];
            #pragma unroll
            for (int rr = 0; rr < 4; ++rr)
                *(float4*)&a[rr][0] = *(const float4*)&sx[r0 + rr][kbase + k];
            #pragma unroll
            for (int j = 0; j < 4; ++j)
                *(float4*)&b[j][0] = *(const float4*)&sW[k + j][c0];
            #pragma unroll
            for (int j = 0; j < 4; ++j)
                #pragma unroll
                for (int rr = 0; rr < 4; ++rr)
                    #pragma unroll
                    for (int cc = 0; cc < 4; ++cc)
                        acc[rr][cc] += a[rr][j] * b[j][cc];
        }
    }

    #pragma unroll
    for (int rr = 0; rr < 4; ++rr) {
        int gr = row0 + r0 + rr;
        if (gr < N) {
            float s = dinv[gr];
            ushort4 o;
            o.x = f2b(acc[rr][0] * s); o.y = f2b(acc[rr][1] * s);
            o.z = f2b(acc[rr][2] * s); o.w = f2b(acc[rr][3] * s);
            *(ushort4*)&xws1b[gr * F1 + c0] = o;
        }
    }
}

// ---- gather1 + gemm2 fused (round-11 MLP-8 shape; round-12 post-mortem:
// MLP-16 regressed — nodes with deg<16 fell to an MLP-4 tail) ----
__global__ __launch_bounds__(256) void gather1f(const int* __restrict__ csr,
                                                const int* __restrict__ rowptr,
                                                const int* __restrict__ deg,
                                                const float* __restrict__ dinv,
                                                const unsigned short* __restrict__ xb,
                                                const float* __restrict__ b1,
                                                const float* __restrict__ W2,
                                                unsigned short* __restrict__ xws2b,
                                                int N, int kh) {
    __shared__ float sW2[F1][F2];    // 8 KB
    __shared__ float h1s[4][F1];     // 1 KB
    int tid = threadIdx.x;
    for (int i = tid; i < (F1 * F2) / 4; i += 256)
        ((float4*)&sW2[0][0])[i] = ((const float4*)W2)[i];
    __syncthreads();

    int wv = tid >> 6, lane = tid & 63;
    int node = blockIdx.x * 4 + wv;
    if (node >= N) return;
    int start = rfl(rowptr[node]);
    int cnt = rfl(deg[node]);

    float a0 = 0.f, a1 = 0.f, a2 = 0.f, a3 = 0.f;
    float a4 = 0.f, a5 = 0.f, a6 = 0.f, a7 = 0.f;
    int j = 0;
    for (; j + 8 <= cnt; j += 8) {
        int s0 = rfl(csr[start + j]);
        int s1 = rfl(csr[start + j + 1]);
        int s2 = rfl(csr[start + j + 2]);
        int s3 = rfl(csr[start + j + 3]);
        int s4 = rfl(csr[start + j + 4]);
        int s5 = rfl(csr[start + j + 5]);
        int s6 = rfl(csr[start + j + 6]);
        int s7 = rfl(csr[start + j + 7]);
        a0 += b2f(xb[s0 * F1 + lane]);
        a1 += b2f(xb[s1 * F1 + lane]);
        a2 += b2f(xb[s2 * F1 + lane]);
        a3 += b2f(xb[s3 * F1 + lane]);
        a4 += b2f(xb[s4 * F1 + lane]);
        a5 += b2f(xb[s5 * F1 + lane]);
        a6 += b2f(xb[s6 * F1 + lane]);
        a7 += b2f(xb[s7 * F1 + lane]);
    }
    for (; j + 4 <= cnt; j += 4) {
        int s0 = rfl(csr[start + j]);
        int s1 = rfl(csr[start + j + 1]);
        int s2 = rfl(csr[start + j + 2]);
        int s3 = rfl(csr[start + j + 3]);
        a0 += b2f(xb[s0 * F1 + lane]);
        a1 += b2f(xb[s1 * F1 + lane]);
        a2 += b2f(xb[s2 * F1 + lane]);
        a3 += b2f(xb[s3 * F1 + lane]);
    }
    for (; j < cnt; ++j) {
        int s = rfl(csr[start + j]);
        a0 += b2f(xb[s * F1 + lane]);
    }
    float acc = ((a0 + a1) + (a2 + a3)) + ((a4 + a5) + (a6 + a7));
    float dd = dinv[node];
    float h1v = fmaxf(dd * (acc + b2f(xb[node * F1 + lane])) + b1[lane], 0.f);

    h1s[wv][lane] = h1v;   // wave-local LDS round-trip

    int c = lane & 31, half = lane >> 5;
    int k0 = half * 32;
    float d0 = 0.f, d1 = 0.f, d2 = 0.f, d3 = 0.f;
    for (int k = 0; k < kh; k += 4) {
        d0 += h1s[wv][k0 + k]     * sW2[k0 + k][c];
        d1 += h1s[wv][k0 + k + 1] * sW2[k0 + k + 1][c];
        d2 += h1s[wv][k0 + k + 2] * sW2[k0 + k + 2][c];
        d3 += h1s[wv][k0 + k + 3] * sW2[k0 + k + 3][c];
    }
    float dot = (d0 + d1) + (d2 + d3);
    dot += __shfl_down(dot, 32, 64);
    if (half == 0) xws2b[node * F2 + c] = f2b(dot * dd);
}

// ---- gather2 + gemm3 fused; `out` written with NON-TEMPORAL stores:
// out is write-once/never-read — avoid L2 RFO + working-set eviction
// (round-12 counters: gather2f FETCH 35.4 MB ≈ inputs + 25.6 MB out RFO). ----
__global__ __launch_bounds__(256) void gather2f(const int* __restrict__ csr,
                                                const int* __restrict__ rowptr,
                                                const int* __restrict__ deg,
                                                const float* __restrict__ dinv,
                                                const unsigned short* __restrict__ xb,
                                                const float* __restrict__ b2,
                                                const float* __restrict__ Wl,
                                                const float* __restrict__ bl,
                                                float* __restrict__ out, int N, int kh) {
    __shared__ float sWl[F2][F0];    // 16 KB
    __shared__ float h2s[4][F2];     // 512 B
    int tid = threadIdx.x;
    for (int i = tid; i < (F2 * F0) / 4; i += 256)
        ((float4*)&sWl[0][0])[i] = ((const float4*)Wl)[i];
    __syncthreads();

    int wv = tid >> 6, lane = tid & 63;
    int node = blockIdx.x * 4 + wv;
    if (node >= N) return;
    int start = rfl(rowptr[node]);
    int cnt = rfl(deg[node]);
    int c = lane & 31, half = lane >> 5;

    float a0 = 0.f, a1 = 0.f, a2 = 0.f, a3 = 0.f;
    int j = 0;
    for (; j + 8 <= cnt; j += 8) {
        int s0 = rfl(csr[start + j]);
        int s1 = rfl(csr[start + j + 1]);
        int s2 = rfl(csr[start + j + 2]);
        int s3 = rfl(csr[start + j + 3]);
        int s4 = rfl(csr[start + j + 4]);
        int s5 = rfl(csr[start + j + 5]);
        int s6 = rfl(csr[start + j + 6]);
        int s7 = rfl(csr[start + j + 7]);
        int sa = half ? s1 : s0;
        int sb = half ? s3 : s2;
        int sc = half ? s5 : s4;
        int sd = half ? s7 : s6;
        a0 += b2f(xb[sa * F2 + c]);
        a1 += b2f(xb[sb * F2 + c]);
        a2 += b2f(xb[sc * F2 + c]);
        a3 += b2f(xb[sd * F2 + c]);
    }
    for (; j + 4 <= cnt; j += 4) {
        int s0 = rfl(csr[start + j]);
        int s1 = rfl(csr[start + j + 1]);
        int s2 = rfl(csr[start + j + 2]);
        int s3 = rfl(csr[start + j + 3]);
        int sa = half ? s1 : s0;
        int sb = half ? s3 : s2;
        a0 += b2f(xb[sa * F2 + c]);
        a1 += b2f(xb[sb * F2 + c]);
    }
    for (; j + 2 <= cnt; j += 2) {
        int s0 = rfl(csr[start + j]);
        int s1 = rfl(csr[start + j + 1]);
        int sa = half ? s1 : s0;
        a0 += b2f(xb[sa * F2 + c]);
    }
    if (j < cnt) {
        int s = rfl(csr[start + j]);
        if (half == 0) a0 += b2f(xb[s * F2 + c]);
    }
    float acc = (a0 + a1) + (a2 + a3);
    acc += __shfl_down(acc, 32, 64);
    float dd = dinv[node];
    if (half == 0)
        h2s[wv][c] = fmaxf(dd * (acc + b2f(xb[node * F2 + c])) + b2[c], 0.f);

    float e0 = 0.f, e1 = 0.f, f0 = 0.f, f1 = 0.f;
    for (int k = 0; k < kh; k += 2) {
        float hk0 = h2s[wv][k], hk1 = h2s[wv][k + 1];
        e0 += hk0 * sWl[k][lane];
        e1 += hk1 * sWl[k + 1][lane];
        f0 += hk0 * sWl[k][lane + 64];
        f1 += hk1 * sWl[k + 1][lane + 64];
    }
    size_t ob = (size_t)node * F0;
    __builtin_nontemporal_store((e0 + e1) + bl[lane],      &out[ob + lane]);
    __builtin_nontemporal_store((f0 + f1) + bl[lane + 64], &out[ob + lane + 64]);
}

extern "C" void kernel_launch(void* const* d_in, const int* in_sizes, int n_in,
                              void* d_out, int out_size, void* d_ws, size_t ws_size,
                              hipStream_t stream) {
    const float* x  = (const float*)d_in[0];
    const int*   ei = (const int*)d_in[1];
    const float* W1 = (const float*)d_in[2];
    const float* b1 = (const float*)d_in[3];
    const float* W2 = (const float*)d_in[4];
    const float* b2 = (const float*)d_in[5];
    const float* Wl = (const float*)d_in[6];
    const float* bl = (const float*)d_in[7];
    float* out = (float*)d_out;

    const int N = in_sizes[0] / F0;   // 50000
    const int E = in_sizes[1] / 2;    // 800000
    const int* src = ei;
    const int* dst = ei + E;
    const int NB = (N + 255) / 256;   // 196

    char* ws = (char*)d_ws;
    size_t off = 0;
    auto alloc = [&](size_t bytes) {
        void* p = ws + off;
        off += (bytes + 255) & ~(size_t)255;
        return p;
    };
    int*            deg    = (int*)alloc((size_t)N * 4);
    float*          dinv   = (float*)alloc((size_t)N * 4);
    int*            rowptr = (int*)alloc((size_t)N * 4);
    int*            cursor = (int*)alloc((size_t)N * 4);
    int*            bsum   = (int*)alloc((size_t)NB * 4);
    int*            boff   = (int*)alloc((size_t)NB * 4);
    int*            csr    = (int*)alloc((size_t)E * 4);
    unsigned short* xws1b  = (unsigned short*)alloc((size_t)N * F1 * 2);
    unsigned short* xws2b  = (unsigned short*)alloc((size_t)N * F2 * 2);

    hipMemsetAsync(deg, 0, (size_t)N * 4, stream);
    deg_count<<<(E + 255) / 256, 256, 0, stream>>>(dst, deg, E);
    scan1<<<NB, 256, 0, stream>>>(deg, dinv, rowptr, bsum, N);
    scan2<<<1, 256, 0, stream>>>(bsum, boff, NB);
    scan3<<<NB, 256, 0, stream>>>(rowptr, boff, cursor, N);
    bucket8<<<1024, 256, 0, stream>>>(src, dst, cursor, csr, E, N);

    gemm1<<<(N + 63) / 64, 256, 0, stream>>>(x, W1, dinv, xws1b, N, 64);
    gather1f<<<(N + 3) / 4, 256, 0, stream>>>(csr, rowptr, deg, dinv, xws1b, b1, W2, xws2b, N, 32);
    gather2f<<<(N + 3) / 4, 256, 0, stream>>>(csr, rowptr, deg, dinv, xws2b, b2, Wl, bl, out, N, 32);
}